// Round 3
// baseline (136.835 us; speedup 1.0000x reference)
//
#include <hip/hip_runtime.h>

// One 64-lane wave per ray; persistent waves, grid-stride over 16 rays each,
// with next-ray prefetch to overlap VMEM latency with the compute spine.
// Intra-ray couplings: DPP (shifts + scans), readlane (bisection head),
// ds_bpermute (bisection tail + final gathers).

template<int CTRL, int RM>
__device__ __forceinline__ float dpp_mov(float old, float x) {
    return __int_as_float(__builtin_amdgcn_update_dpp(
        __float_as_int(old), __float_as_int(x), CTRL, RM, 0xF, false));
}
// row_shr:N = 0x110|N, wave_shl:1 = 0x130, wave_shr:1 = 0x138,
// row_bcast:15 = 0x142, row_bcast:31 = 0x143.  (validated R1: absmax 3.9e-3)

__device__ __forceinline__ float fast_rcp(float x) {
    return __builtin_amdgcn_rcpf(x);
}
__device__ __forceinline__ float rl(float x, int l) {
    return __int_as_float(__builtin_amdgcn_readlane(__float_as_int(x), l));
}

__global__ __launch_bounds__(256) void neus_upsample_kernel(
    const float* __restrict__ rays_o,
    const float* __restrict__ rays_d,
    const float* __restrict__ z_vals,
    const float* __restrict__ sdf,
    const int*   __restrict__ inv_s_ptr,
    float*       __restrict__ out,
    int n_rays)
{
    const int lane   = threadIdx.x & 63;
    const int gwave  = blockIdx.x * 4 + (threadIdx.x >> 6);
    const int stride = gridDim.x * 4;

    const float inv_s = (float)inv_s_ptr[0];
    const float u = ((float)lane + 0.5f) * 0.015625f;   // linspace(1/128, 1-1/128, 64)

    if (gwave >= n_rays) return;

    // ---- prefetch ray 0 ----
    int r = gwave;
    float zc = z_vals[r * 64 + lane];
    float sc = sdf[r * 64 + lane];
    float oxc = rays_o[r*3+0], oyc = rays_o[r*3+1], ozc = rays_o[r*3+2];
    float dxc = rays_d[r*3+0], dyc = rays_d[r*3+1], dzc = rays_d[r*3+2];

    for (; r < n_rays; ) {
        const int nr = r + stride;
        const int pr = (nr < n_rays) ? nr : r;      // clamped prefetch addr
        // ---- issue next ray's loads early ----
        const float zn = z_vals[pr * 64 + lane];
        const float sn = sdf[pr * 64 + lane];
        const float oxn = rays_o[pr*3+0], oyn = rays_o[pr*3+1], ozn = rays_o[pr*3+2];
        const float dxn = rays_d[pr*3+0], dyn = rays_d[pr*3+1], dzn = rays_d[pr*3+2];

        // ---- compute current ray ----
        const float z = zc, s = sc;
        // |o + d z|^2 = z^2 + 2(o.d) z + |o|^2   (|d| == 1)
        const float a  = oxc*oxc + oyc*oyc + ozc*ozc;
        const float b2 = 2.0f * (oxc*dxc + oyc*dyc + ozc*dzc);

        const float z_next = dpp_mov<0x130, 0xF>(z, z);   // from lane+1
        const float s_next = dpp_mov<0x130, 0xF>(s, s);

        const float r2  = fmaf(z,      z      + b2, a);
        const float r2n = fmaf(z_next, z_next + b2, a);
        const float insideE = (fminf(r2, r2n) < 1.0f) ? 1.0f : 0.0f;

        const float cos_raw = (s_next - s) * fast_rcp(z_next - z + 1e-5f);
        float cosv = fminf(dpp_mov<0x138, 0xF>(0.0f, cos_raw), cos_raw); // prev interval
        cosv = fminf(fmaxf(cosv, -1000.0f), 0.0f) * insideE;

        const float mid = 0.5f * (s + s_next);
        const float hd  = 0.5f * (z_next - z);
        const float pe  = fmaf(-cosv, hd, mid);
        const float ne  = fmaf( cosv, hd, mid);
        const float pc  = fast_rcp(1.0f + __expf(-pe * inv_s));
        const float nc  = fast_rcp(1.0f + __expf(-ne * inv_s));
        const float alpha = (pc - nc + 1e-5f) * fast_rcp(pc + 1e-5f);

        // trans = exclusive cumprod of (1 - alpha + 1e-7), intervals 0..62
        float f = (lane < 63) ? (1.0f - alpha + 1e-7f) : 1.0f;
        f *= dpp_mov<0x111, 0xF>(1.0f, f);   // row_shr:1
        f *= dpp_mov<0x112, 0xF>(1.0f, f);   // row_shr:2
        f *= dpp_mov<0x114, 0xF>(1.0f, f);   // row_shr:4
        f *= dpp_mov<0x118, 0xF>(1.0f, f);   // row_shr:8
        f *= dpp_mov<0x142, 0xA>(1.0f, f);   // row_bcast:15 -> rows 1,3
        f *= dpp_mov<0x143, 0xC>(1.0f, f);   // row_bcast:31 -> rows 2,3
        const float trans = dpp_mov<0x138, 0xF>(1.0f, f);

        // weights (+1e-5); lane 63 contributes 0. Inclusive sum scan.
        float q = (lane < 63) ? fmaf(alpha, trans, 1e-5f) : 0.0f;
        q += dpp_mov<0x111, 0xF>(0.0f, q);
        q += dpp_mov<0x112, 0xF>(0.0f, q);
        q += dpp_mov<0x114, 0xF>(0.0f, q);
        q += dpp_mov<0x118, 0xF>(0.0f, q);
        q += dpp_mov<0x142, 0xA>(0.0f, q);
        q += dpp_mov<0x143, 0xC>(0.0f, q);

        const float rtot = fast_rcp(rl(q, 63));
        // Normalized exclusive CDF at index `lane` (C[0]=0, C[63]=1)
        const float C = dpp_mov<0x138, 0xF>(0.0f, q) * rtot;

        // searchsorted(C, u, 'right'): first 3 levels via wave-uniform readlanes
        const float c31 = rl(C, 31);
        const float c15 = rl(C, 15), c47 = rl(C, 47);
        const float c07 = rl(C, 7),  c23 = rl(C, 23);
        const float c39 = rl(C, 39), c55 = rl(C, 55);

        int pos = 0;
        const bool b0 = (c31 <= u);
        if (b0) pos = 32;
        const float l1 = b0 ? c47 : c15;
        const bool b1 = (l1 <= u);
        if (b1) pos += 16;
        const float l2lo = b1 ? c23 : c07;
        const float l2hi = b1 ? c55 : c39;
        const float l2 = b0 ? l2hi : l2lo;
        if (l2 <= u) pos += 8;

        // last 3 levels via dynamic shuffles
        #pragma unroll
        for (int st = 4; st; st >>= 1) {
            const float c = __shfl(C, pos + st - 1);
            if (c <= u) pos += st;
        }
        // pos in [1,63]: below = pos-1, above = pos
        const float cb = __shfl(C, pos - 1);
        const float ca = __shfl(C, pos);
        const float bb = __shfl(z, pos - 1);
        const float ba = __shfl(z, pos);

        float denom = ca - cb;
        denom = (denom < 1e-5f) ? 1.0f : denom;
        const float t = (u - cb) * fast_rcp(denom);

        out[r * 64 + lane] = fmaf(t, ba - bb, bb);

        // ---- rotate prefetched regs ----
        r = nr;
        zc = zn; sc = sn;
        oxc = oxn; oyc = oyn; ozc = ozn;
        dxc = dxn; dyc = dyn; dzc = dzn;
    }
}

extern "C" void kernel_launch(void* const* d_in, const int* in_sizes, int n_in,
                              void* d_out, int out_size, void* d_ws, size_t ws_size,
                              hipStream_t stream) {
    const float* rays_o = (const float*)d_in[0];
    const float* rays_d = (const float*)d_in[1];
    const float* z_vals = (const float*)d_in[2];
    const float* sdf    = (const float*)d_in[3];
    // d_in[4] = n_importance (== 64 == wave width, hardcoded)
    const int*   inv_s  = (const int*)d_in[5];
    float* out = (float*)d_out;

    const int n_rays = in_sizes[0] / 3;   // 131072
    // 2048 blocks x 4 waves = 8192 persistent waves -> 16 rays/wave,
    // 32 waves/CU resident (full occupancy at this VGPR count).
    const int blocks = 2048;

    neus_upsample_kernel<<<blocks, 256, 0, stream>>>(
        rays_o, rays_d, z_vals, sdf, inv_s, out, n_rays);
}